// Round 9
// baseline (517.914 us; speedup 1.0000x reference)
//
#include <hip/hip_runtime.h>
#include <hip/hip_bf16.h>

#define N_NODES 25000
#define N_EDGES 400000
#define NT64 (N_EDGES / 64)   // 6250 exact

typedef __attribute__((ext_vector_type(8))) __bf16 bf16x8;
typedef __attribute__((ext_vector_type(4))) float f32x4;
typedef __attribute__((ext_vector_type(2))) unsigned uint32x2;

// Raw workgroup barrier that does NOT drain vmcnt: waits only LDS ops.
#define BAR() do {                                          \
    asm volatile("s_waitcnt lgkmcnt(0)" ::: "memory");      \
    __builtin_amdgcn_s_barrier();                           \
    asm volatile("" ::: "memory");                          \
} while (0)

static __device__ __forceinline__ unsigned short bfbits(float f) {
    __bf16 h = (__bf16)f;
    return __builtin_bit_cast(unsigned short, h);
}
static __device__ __forceinline__ float ssp_f(float x) {
    // softplus(x) - ln2 = ln2 * (log2(1 + 2^(x*log2e)) - 1); |x| < ~40 here
    const float t = __builtin_amdgcn_exp2f(x * 1.44269504f);
    return 0.69314718f * (__builtin_amdgcn_logf(1.f + t) - 1.f);
}

// ---------------------------------------------------------------------------
// out[M x 256] = op(A[M x 256] @ B[256 x 256] (+ bias))  (unchanged)
// ---------------------------------------------------------------------------
template<int EPI, int OBF, int ABF>
__global__ __launch_bounds__(256, 2)
void node_gemm(const void* __restrict__ Av, const float* __restrict__ B,
               const float* __restrict__ bias, void* __restrict__ outv, int M)
{
    extern __shared__ char lds[];
    const int tid  = threadIdx.x;
    const int half = blockIdx.x & 1;
    const int jblk = half << 7;
    const int row0 = (blockIdx.x >> 1) << 7;

    {
        const int j   = tid & 127;
        const int k2b = (tid >> 7) << 6;
        for (int i = 0; i < 64; ++i) {
            const int k = (k2b + i) * 2;
            const float b0 = B[k * 256 + jblk + j];
            const float b1 = B[(k + 1) * 256 + jblk + j];
            const unsigned pack = (unsigned)bfbits(b0) | ((unsigned)bfbits(b1) << 16);
            *(unsigned*)(lds + ((j * 512 + k * 2) ^ ((j & 7) << 4))) = pack;
        }
    }
    __syncthreads();

    const int wave = tid >> 6;
    const int l    = tid & 63;
    const int lrow = l & 15;
    const int kg   = (l >> 4) << 3;

    f32x4 acc[8][2];
    const f32x4 z4 = {0.f, 0.f, 0.f, 0.f};
    #pragma unroll
    for (int m = 0; m < 8; ++m) { acc[m][0] = z4; acc[m][1] = z4; }

    #pragma unroll
    for (int ks = 0; ks < 8; ++ks) {
        const int k0 = (ks << 5) + kg;
        bf16x8 bfr[2];
        #pragma unroll
        for (int n = 0; n < 2; ++n) {
            const int jl = (wave << 5) + (n << 4) + lrow;
            bfr[n] = *(const bf16x8*)(lds + ((jl * 512 + k0 * 2) ^ ((jl & 7) << 4)));
        }
        #pragma unroll
        for (int m = 0; m < 8; ++m) {
            const int row = row0 + (m << 4) + lrow;
            bf16x8 af;
            if (row < M) {
                if (ABF) {
                    af = *(const bf16x8*)((const __bf16*)Av + row * 256 + k0);
                } else {
                    const float* ap = (const float*)Av + row * 256 + k0;
                    const f32x4 a0 = *(const f32x4*)(ap);
                    const f32x4 a1 = *(const f32x4*)(ap + 4);
                    #pragma unroll
                    for (int b = 0; b < 4; ++b) { af[b] = (__bf16)a0[b]; af[b + 4] = (__bf16)a1[b]; }
                }
            } else {
                #pragma unroll
                for (int b = 0; b < 8; ++b) af[b] = (__bf16)0.f;
            }
            acc[m][0] = __builtin_amdgcn_mfma_f32_16x16x32_bf16(af, bfr[0], acc[m][0], 0, 0, 0);
            acc[m][1] = __builtin_amdgcn_mfma_f32_16x16x32_bf16(af, bfr[1], acc[m][1], 0, 0, 0);
        }
    }

    #pragma unroll
    for (int m = 0; m < 8; ++m) {
        #pragma unroll
        for (int n = 0; n < 2; ++n) {
            const int j = jblk + (wave << 5) + (n << 4) + lrow;
            float bv = 0.f;
            if (EPI) bv = bias[j];
            #pragma unroll
            for (int r = 0; r < 4; ++r) {
                const int row = row0 + (m << 4) + ((l >> 4) << 2) + r;
                if (row < M) {
                    float v = acc[m][n][r] + bv;
                    if (EPI == 1) v = ssp_f(v);
                    if (OBF) ((unsigned short*)outv)[row * 256 + j] = bfbits(v);
                    else     ((float*)outv)[row * 256 + j] = v;
                }
            }
        }
    }
}

// ---------------------------------------------------------------------------
// Counting sort by target col; scatter also precomputes per-edge meta.
// ---------------------------------------------------------------------------
__global__ void hist_kernel(const int* __restrict__ ei, int* __restrict__ hist)
{
    const int i = blockIdx.x * 256 + threadIdx.x;
    if (i < N_EDGES) atomicAdd(&hist[ei[N_EDGES + i]], 1);
}

__global__ void scan_kernel(int* __restrict__ hist)
{
    __shared__ int part[1024];
    const int t  = threadIdx.x;
    const int CH = (N_NODES + 1023) / 1024;   // 25
    const int lo = t * CH;
    const int hi = (lo + CH < N_NODES) ? lo + CH : N_NODES;
    int s = 0;
    for (int i = lo; i < hi; ++i) s += hist[i];
    part[t] = s;
    __syncthreads();
    for (int off = 1; off < 1024; off <<= 1) {
        const int v = part[t];
        const int u = (t >= off) ? part[t - off] : 0;
        __syncthreads();
        part[t] = v + u;
        __syncthreads();
    }
    int base = (t == 0) ? 0 : part[t - 1];
    for (int i = lo; i < hi; ++i) { const int v = hist[i]; hist[i] = base; base += v; }
}

__global__ void scatter_meta(const int* __restrict__ ei, const float* __restrict__ pos,
                             int* __restrict__ hist, float4* __restrict__ meta)
{
    const int i = blockIdx.x * 256 + threadIdx.x;
    if (i >= N_EDGES) return;
    const int r = ei[i];
    const int c = ei[N_EDGES + i];
    const float dx = pos[r * 3 + 0] - pos[c * 3 + 0];
    const float dy = pos[r * 3 + 1] - pos[c * 3 + 1];
    const float dz = pos[r * 3 + 2] - pos[c * 3 + 2];
    const float d  = __fsqrt_rn(dx * dx + dy * dy + dz * dz);
    const float C  = 0.5f * (__cosf(d * 0.31415926535f) + 1.f);
    const int p = atomicAdd(&hist[c], 1);
    float4 m;
    m.x = d; m.y = C;
    m.z = __int_as_float(r); m.w = __int_as_float(c);
    meta[p] = m;
}

// ---------------------------------------------------------------------------
// Fused edge kernel, 512 threads (8 waves), 64-edge tiles, ALL 256 j-cols per
// block. R9 delta vs R8: grid 256 -> 512 blocks (12-13 tile chunks) so
// 2 blocks/CU co-reside (LDS 74KB*2 = 148KB <= 160KB) and barrier stalls of
// one block hide under the other block's compute.
// ---------------------------------------------------------------------------
__global__ __launch_bounds__(512, 2)
void edge_kernel(const float4* __restrict__ meta,
                 const float* __restrict__ w1, const float* __restrict__ b1,
                 const float* __restrict__ w2, const float* __restrict__ b2,
                 const float* __restrict__ x, float* __restrict__ agg)
{
    extern __shared__ char lds[];
    char* tb = lds;                       // 32768
    char* gs = lds + 32768;               //  8192
    char* ms = lds + 40960;               // 32768
    int* colsm = (int*)(lds + 73728);     //   256

    const int tid  = threadIdx.x;
    const int wave = tid >> 6;            // 0..7
    const int l    = tid & 63;
    const int lrow = l & 15;
    const int g    = l >> 4;
    const int kg   = g << 3;
    const int jw   = wave << 5;           // wave's j/filter base (32-wide)

    const float dlt    = 10.f / 49.f;
    const float coeff2 = (-0.5f / (dlt * dlt)) * 1.44269504f;

    // W1 frags: wave owns filter cols [jw, jw+32)
    bf16x8 w1f[2][2];
    #pragma unroll
    for (int n = 0; n < 2; ++n)
        #pragma unroll
        for (int ks = 0; ks < 2; ++ks) {
            bf16x8 v;
            #pragma unroll
            for (int b = 0; b < 8; ++b) {
                const int k = (ks << 5) + kg + b;
                const int j = jw + (n << 4) + lrow;
                v[b] = (k < 50) ? (__bf16)w1[k * 256 + j] : (__bf16)0.f;
            }
            w1f[n][ks] = v;
        }
    // W2 frags: wave owns j-cols [jw, jw+32)
    bf16x8 w2f[2][8];
    #pragma unroll
    for (int n = 0; n < 2; ++n)
        #pragma unroll
        for (int ks = 0; ks < 8; ++ks) {
            bf16x8 v;
            #pragma unroll
            for (int b = 0; b < 8; ++b) {
                const int k = (ks << 5) + kg + b;
                const int j = jw + (n << 4) + lrow;
                v[b] = (__bf16)w2[k * 256 + j];
            }
            w2f[n][ks] = v;
        }
    float b1v[2], b2v[2];
    #pragma unroll
    for (int n = 0; n < 2; ++n) {
        b1v[n] = b1[jw + (n << 4) + lrow];
        b2v[n] = b2[jw + (n << 4) + lrow];
    }

    // contiguous tile chunks over 512 groups: 106 of 13, 406 of 12 (6250)
    const int group = blockIdx.x;
    int t0, t1;
    if (group < 106) { t0 = group * 13; t1 = t0 + 13; }
    else             { t0 = 1378 + (group - 106) * 12; t1 = t0 + 12; }

    const f32x4 z4 = {0.f, 0.f, 0.f, 0.f};
    const int ge  = tid >> 3;         // gaussian producer: edge 0..63
    const int gkb = (tid & 7) << 3;   // gaussian producer: k-base

    for (int t = t0; t < t1; ++t) {
        // meta: every wave loads all 64 edges (lane l = edge l), L2-hot
        const float4 mv = meta[(t << 6) + l];
        const float d  = mv.x;
        const float Cc = mv.y;
        const int   r  = __float_as_int(mv.z);
        const int   c  = __float_as_int(mv.w);

        // T14 hoist: 32 x-gather loads; lgkm-only barriers keep them in
        // flight until the msg epilogue.
        float xv[4][2][4];
        #pragma unroll
        for (int m = 0; m < 4; ++m)
            #pragma unroll
            for (int r4 = 0; r4 < 4; ++r4) {
                const int e  = (m << 4) + (g << 2) + r4;
                const int re = __shfl(r, e, 64);
                #pragma unroll
                for (int n = 0; n < 2; ++n)
                    xv[m][n][r4] = x[re * 256 + jw + (n << 4) + lrow];
            }

        // gaussians: thread (ge, gkb) computes 8 k-values for edge ge
        const float gd = __shfl(d, ge, 64);
        bf16x8 gv;
        #pragma unroll
        for (int b = 0; b < 8; ++b) {
            const int k = gkb + b;
            float gval = 0.f;
            if (k < 50) {
                const float u = gd - (float)k * dlt;
                gval = __builtin_amdgcn_exp2f(coeff2 * u * u);
            }
            gv[b] = (__bf16)gval;
        }
        // gs disjoint from ms: safe to write while prev-tile reader reads ms
        *(bf16x8*)(gs + ((ge * 128 + (gkb << 1)) ^ ((ge & 7) << 4))) = gv;
        BAR();   // A: gauss ready (also: prev reader done before tb write below)

        // ---- GEMM1: gauss[64][64] @ W1[:, jw:jw+32] -> acc1[4][2]
        f32x4 acc1[4][2];
        #pragma unroll
        for (int m = 0; m < 4; ++m) { acc1[m][0] = z4; acc1[m][1] = z4; }
        #pragma unroll
        for (int ks = 0; ks < 2; ++ks) {
            #pragma unroll
            for (int m = 0; m < 4; ++m) {
                const int e = (m << 4) + lrow;
                const bf16x8 af = *(const bf16x8*)(gs + ((e * 128 + (((ks << 5) + kg) << 1)) ^ ((e & 7) << 4)));
                #pragma unroll
                for (int n = 0; n < 2; ++n)
                    acc1[m][n] = __builtin_amdgcn_mfma_f32_16x16x32_bf16(af, w1f[n][ks], acc1[m][n], 0, 0, 0);
            }
        }
        // epilogue1: t = ssp(acc1 + b1) -> tb bf16 (swizzled)
        #pragma unroll
        for (int m = 0; m < 4; ++m)
            #pragma unroll
            for (int n = 0; n < 2; ++n)
                #pragma unroll
                for (int r4 = 0; r4 < 4; ++r4) {
                    const int e = (m << 4) + (g << 2) + r4;
                    const int k = jw + (n << 4) + lrow;
                    const float v = ssp_f(acc1[m][n][r4] + b1v[n]);
                    *(__bf16*)(tb + ((e * 512 + k * 2) ^ ((e & 7) << 4))) = (__bf16)v;
                }
        BAR();   // B: tb ready

        // ---- GEMM2: t[64][256] @ W2[:, jw:jw+32] -> acc2[4][2]
        f32x4 acc2[4][2];
        #pragma unroll
        for (int m = 0; m < 4; ++m) { acc2[m][0] = z4; acc2[m][1] = z4; }
        #pragma unroll
        for (int ks = 0; ks < 8; ++ks) {
            const int k0 = (ks << 5) + kg;
            #pragma unroll
            for (int m = 0; m < 4; ++m) {
                const int e = (m << 4) + lrow;
                const bf16x8 a = *(const bf16x8*)(tb + ((e * 512 + k0 * 2) ^ ((e & 7) << 4)));
                #pragma unroll
                for (int n = 0; n < 2; ++n)
                    acc2[m][n] = __builtin_amdgcn_mfma_f32_16x16x32_bf16(a, w2f[n][ks], acc2[m][n], 0, 0, 0);
            }
        }

        // ---- msg: (acc2+b2)*C * xv -> ms[j][e] bf16 (swizzled)
        #pragma unroll
        for (int m = 0; m < 4; ++m) {
            const int base_e = (m << 4) + (g << 2);
            #pragma unroll
            for (int n = 0; n < 2; ++n) {
                const int j = jw + (n << 4) + lrow;
                float vv[4];
                #pragma unroll
                for (int r4 = 0; r4 < 4; ++r4) {
                    const int e  = base_e + r4;
                    const float Ce = __shfl(Cc, e, 64);
                    vv[r4] = (acc2[m][n][r4] + b2v[n]) * Ce * xv[m][n][r4];
                }
                uint32x2 pk;
                pk[0] = (unsigned)bfbits(vv[0]) | ((unsigned)bfbits(vv[1]) << 16);
                pk[1] = (unsigned)bfbits(vv[2]) | ((unsigned)bfbits(vv[3]) << 16);
                *(uint32x2*)(ms + ((j * 128 + (base_e << 1)) ^ ((j & 7) << 4))) = pk;
            }
        }
        if (tid < 64) colsm[tid] = c;   // wave0 lanes hold col of edge l
        BAR();   // C: msg + cols ready

        // ---- reader: 512 threads = 256 j x 2 e-halves; run-length reduce
        {
            const int j  = tid & 255;
            const int eh = (tid >> 8) << 5;     // 0 or 32
            const bf16x8 q0 = *(const bf16x8*)(ms + ((j * 128 + (eh << 1)     ) ^ ((j & 7) << 4)));
            const bf16x8 q1 = *(const bf16x8*)(ms + ((j * 128 + (eh << 1) + 16) ^ ((j & 7) << 4)));
            const bf16x8 q2 = *(const bf16x8*)(ms + ((j * 128 + (eh << 1) + 32) ^ ((j & 7) << 4)));
            const bf16x8 q3 = *(const bf16x8*)(ms + ((j * 128 + (eh << 1) + 48) ^ ((j & 7) << 4)));
            float* aj = agg + j;
            int prev = colsm[eh];
            float s = 0.f;
            #pragma unroll
            for (int e = 0; e < 32; ++e) {
                const float v = (float)(e < 8 ? q0[e] : e < 16 ? q1[e - 8] :
                                        e < 24 ? q2[e - 16] : q3[e - 24]);
                const int ce = colsm[eh + e];
                if (ce != prev) { atomicAdd(aj + prev * 256, s); s = 0.f; prev = ce; }
                s += v;
            }
            atomicAdd(aj + prev * 256, s);
        }
    }
}

__global__ void copy_pos_kernel(const float* __restrict__ p, float* __restrict__ o, int n)
{
    const int i = blockIdx.x * 256 + threadIdx.x;
    if (i < n) o[i] = p[i];
}

extern "C" void kernel_launch(void* const* d_in, const int* in_sizes, int n_in,
                              void* d_out, int out_size, void* d_ws, size_t ws_size,
                              hipStream_t stream)
{
    const float* h      = (const float*)d_in[0];
    const float* pos    = (const float*)d_in[1];
    const float* lin1_w = (const float*)d_in[2];
    const float* lin2_w = (const float*)d_in[3];
    const float* lin2_b = (const float*)d_in[4];
    const float* mlp_w1 = (const float*)d_in[5];
    const float* mlp_b1 = (const float*)d_in[6];
    const float* mlp_w2 = (const float*)d_in[7];
    const float* mlp_b2 = (const float*)d_in[8];
    const float* lin_w  = (const float*)d_in[9];
    const float* lin_b  = (const float*)d_in[10];
    const int*   ei     = (const int*)d_in[11];
    float* out = (float*)d_out;

    // ws layout: x f32 | agg f32 | meta | hist ; xb aliases x (dead by then)
    float*  x    = (float*)d_ws;                               // 25,600,000 B
    float*  agg  = (float*)((char*)d_ws + 25600000);           // 25,600,000 B
    float4* meta = (float4*)((char*)d_ws + 51200000);          //  6,400,000 B
    int*    hist = (int*)((char*)d_ws + 57600000);             //    100,000 B
    unsigned short* xb = (unsigned short*)d_ws;                // aliases x

    (void)hipFuncSetAttribute((const void*)edge_kernel,
                              hipFuncAttributeMaxDynamicSharedMemorySize, 73984);
    (void)hipFuncSetAttribute((const void*)node_gemm<0, 0, 0>,
                              hipFuncAttributeMaxDynamicSharedMemorySize, 65536);
    (void)hipFuncSetAttribute((const void*)node_gemm<1, 1, 0>,
                              hipFuncAttributeMaxDynamicSharedMemorySize, 65536);
    (void)hipFuncSetAttribute((const void*)node_gemm<2, 0, 1>,
                              hipFuncAttributeMaxDynamicSharedMemorySize, 65536);

    (void)hipMemsetAsync(agg, 0, (size_t)N_NODES * 256 * sizeof(float), stream);
    (void)hipMemsetAsync(hist, 0, (size_t)N_NODES * sizeof(int), stream);

    const dim3 blk(256);
    const int mt = (N_NODES + 127) / 128;   // 196 row-tiles
    const int eb = (N_EDGES + 255) / 256;   // 1563 blocks

    // x = h @ lin1_w  (f32 out)
    node_gemm<0, 0, 0><<<dim3(mt * 2), blk, 65536, stream>>>(h, lin1_w, nullptr, x, N_NODES);

    // counting sort by col + per-edge meta (d, C, r, c)
    hist_kernel<<<dim3(eb), blk, 0, stream>>>(ei, hist);
    scan_kernel<<<dim3(1), dim3(1024), 0, stream>>>(hist);
    scatter_meta<<<dim3(eb), blk, 0, stream>>>(ei, pos, hist, meta);

    // fused edge pipeline -> agg  (512 threads, 64-edge tiles, 512 blocks)
    edge_kernel<<<dim3(512), dim3(512), 73984, stream>>>(meta, mlp_w1, mlp_b1,
                                                         mlp_w2, mlp_b2, x, agg);

    // x2 = bf16(ssp(agg @ lin2_w + lin2_b))  (writes xb, aliasing dead x)
    node_gemm<1, 1, 0><<<dim3(mt * 2), blk, 65536, stream>>>(agg, lin2_w, lin2_b, xb, N_NODES);
    // h_update = x2 @ lin_w + lin_b
    node_gemm<2, 0, 1><<<dim3(mt * 2), blk, 65536, stream>>>(xb, lin_w, lin_b, out, N_NODES);
    // pos passthrough
    copy_pos_kernel<<<dim3((N_NODES * 3 + 255) / 256), blk, 0, stream>>>(pos, out + N_NODES * 256, N_NODES * 3);
}

// Round 10
// 447.510 us; speedup vs baseline: 1.1573x; 1.1573x over previous
//
#include <hip/hip_runtime.h>
#include <hip/hip_bf16.h>

#define N_NODES 25000
#define N_EDGES 400000
#define NTILES (N_EDGES / 32)   // 12500 exact

typedef __attribute__((ext_vector_type(8))) __bf16 bf16x8;
typedef __attribute__((ext_vector_type(4))) float f32x4;
typedef __attribute__((ext_vector_type(2))) unsigned uint32x2;

// Raw workgroup barrier that does NOT drain vmcnt: waits only LDS ops.
#define BAR() do {                                          \
    asm volatile("s_waitcnt lgkmcnt(0)" ::: "memory");      \
    __builtin_amdgcn_s_barrier();                           \
    asm volatile("" ::: "memory");                          \
} while (0)

static __device__ __forceinline__ unsigned short bfbits(float f) {
    __bf16 h = (__bf16)f;
    return __builtin_bit_cast(unsigned short, h);
}
static __device__ __forceinline__ float ssp_f(float x) {
    // softplus(x) - ln2 = ln2 * (log2(1 + 2^(x*log2e)) - 1); |x| < ~40 here
    const float t = __builtin_amdgcn_exp2f(x * 1.44269504f);
    return 0.69314718f * (__builtin_amdgcn_logf(1.f + t) - 1.f);
}

// ---------------------------------------------------------------------------
// out[M x 256] = op(A[M x 256] @ B[256 x 256] (+ bias))  (R7, unchanged)
// ---------------------------------------------------------------------------
template<int EPI, int OBF, int ABF>
__global__ __launch_bounds__(256, 2)
void node_gemm(const void* __restrict__ Av, const float* __restrict__ B,
               const float* __restrict__ bias, void* __restrict__ outv, int M)
{
    extern __shared__ char lds[];
    const int tid  = threadIdx.x;
    const int half = blockIdx.x & 1;
    const int jblk = half << 7;
    const int row0 = (blockIdx.x >> 1) << 7;

    {
        const int j   = tid & 127;
        const int k2b = (tid >> 7) << 6;
        for (int i = 0; i < 64; ++i) {
            const int k = (k2b + i) * 2;
            const float b0 = B[k * 256 + jblk + j];
            const float b1 = B[(k + 1) * 256 + jblk + j];
            const unsigned pack = (unsigned)bfbits(b0) | ((unsigned)bfbits(b1) << 16);
            *(unsigned*)(lds + ((j * 512 + k * 2) ^ ((j & 7) << 4))) = pack;
        }
    }
    __syncthreads();

    const int wave = tid >> 6;
    const int l    = tid & 63;
    const int lrow = l & 15;
    const int kg   = (l >> 4) << 3;

    f32x4 acc[8][2];
    const f32x4 z4 = {0.f, 0.f, 0.f, 0.f};
    #pragma unroll
    for (int m = 0; m < 8; ++m) { acc[m][0] = z4; acc[m][1] = z4; }

    #pragma unroll
    for (int ks = 0; ks < 8; ++ks) {
        const int k0 = (ks << 5) + kg;
        bf16x8 bfr[2];
        #pragma unroll
        for (int n = 0; n < 2; ++n) {
            const int jl = (wave << 5) + (n << 4) + lrow;
            bfr[n] = *(const bf16x8*)(lds + ((jl * 512 + k0 * 2) ^ ((jl & 7) << 4)));
        }
        #pragma unroll
        for (int m = 0; m < 8; ++m) {
            const int row = row0 + (m << 4) + lrow;
            bf16x8 af;
            if (row < M) {
                if (ABF) {
                    af = *(const bf16x8*)((const __bf16*)Av + row * 256 + k0);
                } else {
                    const float* ap = (const float*)Av + row * 256 + k0;
                    const f32x4 a0 = *(const f32x4*)(ap);
                    const f32x4 a1 = *(const f32x4*)(ap + 4);
                    #pragma unroll
                    for (int b = 0; b < 4; ++b) { af[b] = (__bf16)a0[b]; af[b + 4] = (__bf16)a1[b]; }
                }
            } else {
                #pragma unroll
                for (int b = 0; b < 8; ++b) af[b] = (__bf16)0.f;
            }
            acc[m][0] = __builtin_amdgcn_mfma_f32_16x16x32_bf16(af, bfr[0], acc[m][0], 0, 0, 0);
            acc[m][1] = __builtin_amdgcn_mfma_f32_16x16x32_bf16(af, bfr[1], acc[m][1], 0, 0, 0);
        }
    }

    #pragma unroll
    for (int m = 0; m < 8; ++m) {
        #pragma unroll
        for (int n = 0; n < 2; ++n) {
            const int j = jblk + (wave << 5) + (n << 4) + lrow;
            float bv = 0.f;
            if (EPI) bv = bias[j];
            #pragma unroll
            for (int r = 0; r < 4; ++r) {
                const int row = row0 + (m << 4) + ((l >> 4) << 2) + r;
                if (row < M) {
                    float v = acc[m][n][r] + bv;
                    if (EPI == 1) v = ssp_f(v);
                    if (OBF) ((unsigned short*)outv)[row * 256 + j] = bfbits(v);
                    else     ((float*)outv)[row * 256 + j] = v;
                }
            }
        }
    }
}

// ---------------------------------------------------------------------------
// Counting sort by target col; scatter also precomputes per-edge meta and
// copies the pos passthrough into the output (fused, saves a launch).
// ---------------------------------------------------------------------------
__global__ void hist_kernel(const int* __restrict__ ei, int* __restrict__ hist)
{
    const int i = blockIdx.x * 256 + threadIdx.x;
    if (i < N_EDGES) atomicAdd(&hist[ei[N_EDGES + i]], 1);
}

__global__ void scan_kernel(int* __restrict__ hist)
{
    __shared__ int part[1024];
    const int t  = threadIdx.x;
    const int CH = (N_NODES + 1023) / 1024;   // 25
    const int lo = t * CH;
    const int hi = (lo + CH < N_NODES) ? lo + CH : N_NODES;
    int s = 0;
    for (int i = lo; i < hi; ++i) s += hist[i];
    part[t] = s;
    __syncthreads();
    for (int off = 1; off < 1024; off <<= 1) {
        const int v = part[t];
        const int u = (t >= off) ? part[t - off] : 0;
        __syncthreads();
        part[t] = v + u;
        __syncthreads();
    }
    int base = (t == 0) ? 0 : part[t - 1];
    for (int i = lo; i < hi; ++i) { const int v = hist[i]; hist[i] = base; base += v; }
}

__global__ void scatter_meta(const int* __restrict__ ei, const float* __restrict__ pos,
                             int* __restrict__ hist, float4* __restrict__ meta,
                             float* __restrict__ out_pos)
{
    const int i = blockIdx.x * 256 + threadIdx.x;
    if (i >= N_EDGES) return;
    if (i < N_NODES * 3) out_pos[i] = pos[i];   // fused pos passthrough
    const int r = ei[i];
    const int c = ei[N_EDGES + i];
    const float dx = pos[r * 3 + 0] - pos[c * 3 + 0];
    const float dy = pos[r * 3 + 1] - pos[c * 3 + 1];
    const float dz = pos[r * 3 + 2] - pos[c * 3 + 2];
    const float d  = __fsqrt_rn(dx * dx + dy * dy + dz * dz);
    const float C  = 0.5f * (__cosf(d * 0.31415926535f) + 1.f);
    const int p = atomicAdd(&hist[c], 1);
    float4 m;
    m.x = d; m.y = C;
    m.z = __int_as_float(r); m.w = __int_as_float(c);
    meta[p] = m;
}

// ---------------------------------------------------------------------------
// Fused edge kernel over SORTED edges (R7 structure: half-width blocks,
// W2^T in LDS 64KB, 16KB union rb, 6 lgkm-only barriers/tile, 512 blocks,
// contiguous 49-tile chunks, f32 x-gather hoisted).
// R10 delta: reader carries (prev,sum) ACROSS tiles in the chunk; interior
// runs are sole-writer (global col-sort) -> plain f32 store; only the
// chunk's first and last runs use atomicAdd.
// ---------------------------------------------------------------------------
__global__ __launch_bounds__(256, 2)
void edge_kernel(const float4* __restrict__ meta,
                 const float* __restrict__ w1, const float* __restrict__ b1,
                 const float* __restrict__ w2, const float* __restrict__ b2,
                 const float* __restrict__ x, float* __restrict__ agg)
{
    extern __shared__ char lds[];
    char* w2t = lds;
    char* rb  = lds + 65536;
    int* colsm = (int*)(rb + 8192);

    const int tid   = threadIdx.x;
    const int wave  = tid >> 6;
    const int l     = tid & 63;
    const int lrow  = l & 15;
    const int g     = l >> 4;
    const int kg    = g << 3;
    const int half  = blockIdx.x & 1;
    const int jblk  = half << 7;
    const int group = blockIdx.x >> 1;

    // stage W2^T half
    {
        const int j   = tid & 127;
        const int k2b = (tid >> 7) << 6;
        for (int i = 0; i < 64; ++i) {
            const int k = (k2b + i) * 2;
            const float v0 = w2[k * 256 + jblk + j];
            const float v1 = w2[(k + 1) * 256 + jblk + j];
            const unsigned pack = (unsigned)bfbits(v0) | ((unsigned)bfbits(v1) << 16);
            *(unsigned*)(w2t + ((j * 512 + k * 2) ^ ((j & 7) << 4))) = pack;
        }
    }

    // W1 B-fragments in registers (wave owns 64 filter cols)
    const float dlt    = 10.f / 49.f;
    const float coeff2 = (-0.5f / (dlt * dlt)) * 1.44269504f;   // log2e folded
    bf16x8 w1f[4][2];
    #pragma unroll
    for (int n = 0; n < 4; ++n)
        #pragma unroll
        for (int ks = 0; ks < 2; ++ks) {
            bf16x8 v;
            #pragma unroll
            for (int b = 0; b < 8; ++b) {
                const int k = (ks << 5) + kg + b;
                const int j = (wave << 6) + (n << 4) + lrow;
                v[b] = (k < 50) ? (__bf16)w1[k * 256 + j] : (__bf16)0.f;
            }
            w1f[n][ks] = v;
        }
    float b1v[4], b2v[2];
    #pragma unroll
    for (int n = 0; n < 4; ++n) b1v[n] = b1[(wave << 6) + (n << 4) + lrow];
    #pragma unroll
    for (int n = 0; n < 2; ++n) b2v[n] = b2[jblk + (wave << 5) + (n << 4) + lrow];

    BAR();   // w2t ready

    const f32x4 z4 = {0.f, 0.f, 0.f, 0.f};
    const int CH = (NTILES + 255) / 256;    // 49 tiles per group, contiguous
    const int t0 = group * CH;
    int t1 = t0 + CH; if (t1 > NTILES) t1 = NTILES;

    const int ge  = tid >> 3;         // gaussian producer: edge 0..31
    const int gkb = (tid & 7) << 3;   // gaussian producer: k-base

    // reader run-carry state (used by tid < 128 only)
    int   rprev  = -1;
    float rs     = 0.f;
    int   rfirst = 1;
    float* aj    = agg + jblk + (tid & 127);

    for (int t = t0; t < t1; ++t) {
        // coalesced meta: lane l&31 owns edge (t<<5) + (l&31)
        const float4 mv = meta[(t << 5) + (l & 31)];
        const float d  = mv.x;
        const float Cc = mv.y;
        const int   r  = __float_as_int(mv.z);
        const int   c  = __float_as_int(mv.w);

        // T14 hoist: issue the 16 x-gather loads now; with lgkm-only barriers
        // they stay in flight until the msg epilogue (first register use).
        float xv[2][2][4];
        #pragma unroll
        for (int m = 0; m < 2; ++m)
            #pragma unroll
            for (int r4 = 0; r4 < 4; ++r4) {
                const int e  = (m << 4) + (g << 2) + r4;
                const int re = __shfl(r, e, 64);
                #pragma unroll
                for (int n = 0; n < 2; ++n) {
                    const int jloc = (wave << 5) + (n << 4) + lrow;
                    xv[m][n][r4] = x[re * 256 + jblk + jloc];
                }
            }

        // gaussian producer: thread (ge, gkb) computes 8 k-values for edge ge
        const float gd = __shfl(d, ge, 64);
        bf16x8 gv;
        #pragma unroll
        for (int b = 0; b < 8; ++b) {
            const int k = gkb + b;
            float gval = 0.f;
            if (k < 50) {
                const float u = gd - (float)k * dlt;
                gval = __builtin_amdgcn_exp2f(coeff2 * u * u);
            }
            gv[b] = (__bf16)gval;
        }

        BAR();   // B1: previous iteration's readers done with rb
        *(bf16x8*)(rb + ((ge * 128 + (gkb << 1)) ^ ((ge & 7) << 4))) = gv;
        BAR();   // B2: gaussians visible

        // ---- GEMM1: gauss[32][64] @ W1 -> acc1 (wave owns 64 filter cols)
        bf16x8 af[2][2];
        #pragma unroll
        for (int m = 0; m < 2; ++m) {
            const int e = (m << 4) + lrow;
            #pragma unroll
            for (int ks = 0; ks < 2; ++ks)
                af[m][ks] = *(const bf16x8*)(rb + ((e * 128 + ((ks << 5) + kg) * 2) ^ ((e & 7) << 4)));
        }
        f32x4 acc1[2][4];
        #pragma unroll
        for (int m = 0; m < 2; ++m)
            #pragma unroll
            for (int n = 0; n < 4; ++n) acc1[m][n] = z4;
        #pragma unroll
        for (int ks = 0; ks < 2; ++ks)
            #pragma unroll
            for (int m = 0; m < 2; ++m)
                #pragma unroll
                for (int n = 0; n < 4; ++n)
                    acc1[m][n] = __builtin_amdgcn_mfma_f32_16x16x32_bf16(af[m][ks], w1f[n][ks], acc1[m][n], 0, 0, 0);
        BAR();   // B3: gauss reads done; tb region writable

        // ---- epilogue1: t = ssp(acc1 + b1) -> tb bf16 (swizzled)
        #pragma unroll
        for (int m = 0; m < 2; ++m)
            #pragma unroll
            for (int n = 0; n < 4; ++n)
                #pragma unroll
                for (int r4 = 0; r4 < 4; ++r4) {
                    const int e = (m << 4) + (g << 2) + r4;
                    const int k = (wave << 6) + (n << 4) + lrow;
                    const float v = ssp_f(acc1[m][n][r4] + b1v[n]);
                    *(__bf16*)(rb + ((e * 512 + k * 2) ^ ((e & 7) << 4))) = (__bf16)v;
                }
        BAR();   // B4: tb ready

        // ---- GEMM2: t[32][256] @ W2[:, jblk:+128] -> acc2
        f32x4 acc2[2][2];
        #pragma unroll
        for (int m = 0; m < 2; ++m) { acc2[m][0] = z4; acc2[m][1] = z4; }
        #pragma unroll
        for (int ks = 0; ks < 8; ++ks) {
            const int k0 = (ks << 5) + kg;
            bf16x8 bfr[2];
            #pragma unroll
            for (int n = 0; n < 2; ++n) {
                const int jl = (wave << 5) + (n << 4) + lrow;
                bfr[n] = *(const bf16x8*)(w2t + ((jl * 512 + k0 * 2) ^ ((jl & 7) << 4)));
            }
            #pragma unroll
            for (int m = 0; m < 2; ++m) {
                const int e = (m << 4) + lrow;
                const bf16x8 a = *(const bf16x8*)(rb + ((e * 512 + k0 * 2) ^ ((e & 7) << 4)));
                #pragma unroll
                for (int n = 0; n < 2; ++n)
                    acc2[m][n] = __builtin_amdgcn_mfma_f32_16x16x32_bf16(a, bfr[n], acc2[m][n], 0, 0, 0);
            }
        }
        BAR();   // B5: tb reads done; msg region writable

        // ---- msg epilogue: (acc2+b2)*C * xv -> msg[j][e] bf16 (swizzled)
        #pragma unroll
        for (int m = 0; m < 2; ++m) {
            const int base_e = (m << 4) + (g << 2);
            #pragma unroll
            for (int n = 0; n < 2; ++n) {
                const int jloc = (wave << 5) + (n << 4) + lrow;
                float vv[4];
                #pragma unroll
                for (int r4 = 0; r4 < 4; ++r4) {
                    const int e  = base_e + r4;
                    const float Ce = __shfl(Cc, e, 64);
                    vv[r4] = (acc2[m][n][r4] + b2v[n]) * Ce * xv[m][n][r4];
                }
                uint32x2 pk;
                pk[0] = (unsigned)bfbits(vv[0]) | ((unsigned)bfbits(vv[1]) << 16);
                pk[1] = (unsigned)bfbits(vv[2]) | ((unsigned)bfbits(vv[3]) << 16);
                *(uint32x2*)(rb + ((jloc * 64 + (base_e << 1)) ^ ((jloc & 7) << 4))) = pk;
            }
        }
        if (tid < 32) colsm[tid] = c;
        BAR();   // B6: msg + cols ready

        // ---- reader: 128 threads, one j each, 32 edges; run-carry reduce.
        // Sorted cols: each col is one contiguous global run. Interior runs
        // (start AND end observed inside this chunk) are sole-writer ->
        // plain store. First run (may extend into prev chunk) and the final
        // run (may extend into next chunk) use atomicAdd.
        if (tid < 128) {
            const int j = tid;
            const bf16x8 q0 = *(const bf16x8*)(rb + ((j * 64 +  0) ^ ((j & 7) << 4)));
            const bf16x8 q1 = *(const bf16x8*)(rb + ((j * 64 + 16) ^ ((j & 7) << 4)));
            const bf16x8 q2 = *(const bf16x8*)(rb + ((j * 64 + 32) ^ ((j & 7) << 4)));
            const bf16x8 q3 = *(const bf16x8*)(rb + ((j * 64 + 48) ^ ((j & 7) << 4)));
            #pragma unroll
            for (int e = 0; e < 32; ++e) {
                const float v = (float)(e < 8 ? q0[e] : e < 16 ? q1[e - 8] :
                                        e < 24 ? q2[e - 16] : q3[e - 24]);
                const int ce = colsm[e];
                if (ce != rprev) {                    // wave-uniform branch
                    if (rprev >= 0) {
                        if (rfirst) { atomicAdd(aj + rprev * 256, rs); rfirst = 0; }
                        else        { aj[rprev * 256] = rs; }
                    }
                    rs = 0.f; rprev = ce;
                }
                rs += v;
            }
        }
    }
    // final flush: run may continue into the next chunk -> atomic
    if (tid < 128 && rprev >= 0) atomicAdd(aj + rprev * 256, rs);
}

extern "C" void kernel_launch(void* const* d_in, const int* in_sizes, int n_in,
                              void* d_out, int out_size, void* d_ws, size_t ws_size,
                              hipStream_t stream)
{
    const float* h      = (const float*)d_in[0];
    const float* pos    = (const float*)d_in[1];
    const float* lin1_w = (const float*)d_in[2];
    const float* lin2_w = (const float*)d_in[3];
    const float* lin2_b = (const float*)d_in[4];
    const float* mlp_w1 = (const float*)d_in[5];
    const float* mlp_b1 = (const float*)d_in[6];
    const float* mlp_w2 = (const float*)d_in[7];
    const float* mlp_b2 = (const float*)d_in[8];
    const float* lin_w  = (const float*)d_in[9];
    const float* lin_b  = (const float*)d_in[10];
    const int*   ei     = (const int*)d_in[11];
    float* out = (float*)d_out;

    // ws layout: x f32 | agg f32 | meta | hist ; xb aliases x (dead by then)
    float*  x    = (float*)d_ws;                               // 25,600,000 B
    float*  agg  = (float*)((char*)d_ws + 25600000);           // 25,600,000 B
    float4* meta = (float4*)((char*)d_ws + 51200000);          //  6,400,000 B
    int*    hist = (int*)((char*)d_ws + 57600000);             //    100,000 B
    unsigned short* xb = (unsigned short*)d_ws;                // aliases x

    (void)hipFuncSetAttribute((const void*)edge_kernel,
                              hipFuncAttributeMaxDynamicSharedMemorySize, 81920);
    (void)hipFuncSetAttribute((const void*)node_gemm<0, 0, 0>,
                              hipFuncAttributeMaxDynamicSharedMemorySize, 65536);
    (void)hipFuncSetAttribute((const void*)node_gemm<1, 1, 0>,
                              hipFuncAttributeMaxDynamicSharedMemorySize, 65536);
    (void)hipFuncSetAttribute((const void*)node_gemm<2, 0, 1>,
                              hipFuncAttributeMaxDynamicSharedMemorySize, 65536);

    (void)hipMemsetAsync(agg, 0, (size_t)N_NODES * 256 * sizeof(float), stream);
    (void)hipMemsetAsync(hist, 0, (size_t)N_NODES * sizeof(int), stream);

    const dim3 blk(256);
    const int mt = (N_NODES + 127) / 128;   // 196 row-tiles
    const int eb = (N_EDGES + 255) / 256;   // 1563 blocks

    // x = h @ lin1_w  (f32 out)
    node_gemm<0, 0, 0><<<dim3(mt * 2), blk, 65536, stream>>>(h, lin1_w, nullptr, x, N_NODES);

    // counting sort by col + per-edge meta (d, C, r, c) + fused pos copy
    hist_kernel<<<dim3(eb), blk, 0, stream>>>(ei, hist);
    scan_kernel<<<dim3(1), dim3(1024), 0, stream>>>(hist);
    scatter_meta<<<dim3(eb), blk, 0, stream>>>(ei, pos, hist, meta, out + N_NODES * 256);

    // fused edge pipeline -> agg
    edge_kernel<<<dim3(512), blk, 81920, stream>>>(meta, mlp_w1, mlp_b1,
                                                   mlp_w2, mlp_b2, x, agg);

    // x2 = bf16(ssp(agg @ lin2_w + lin2_b))  (writes xb, aliasing dead x)
    node_gemm<1, 1, 0><<<dim3(mt * 2), blk, 65536, stream>>>(agg, lin2_w, lin2_b, xb, N_NODES);
    // h_update = x2 @ lin_w + lin_b
    node_gemm<2, 0, 1><<<dim3(mt * 2), blk, 65536, stream>>>(xb, lin_w, lin_b, out, N_NODES);
}